// Round 3
// 207.593 us; speedup vs baseline: 1.0182x; 1.0182x over previous
//
#include <hip/hip_runtime.h>

// topk cross-entropy: N=262144 rows, C=128 classes, K = int(0.7*N) = 183500.
// Round 9b (fix compile: __builtin_nontemporal_load needs a clang ext_vector
// pointer, not HIP_vector_type float4): (a) target logit extracted
// IN-REGISTER (quad shuffle broadcast of t + 3-level select tree + quad
// shuffle-sum) — removes the per-row scattered 64B gather (~16 MB HBM +
// dependent-load stall); (b) hist2/hsum2/fine zeroing folded into loss_hist
// (1 store/thread, overlapped with load latency) — memset node shrinks
// 4.4MB -> 128KiB (hist1 only, must pre-zero due to atomic race);
// (c) nontemporal loads for the streamed input.
// 4 nodes: memset(128K) -> loss+hist12(+zero aux) -> refine(+scan1)+sums
// -> finalize(1 blk). NO device-scope fences (R4/R5/R6: ~us/block on CDNA4).
// Exact 12/10/10-bit radix select on float bits (losses >= 0 => monotone);
// tie-exact mean = (S1 + S2 + S3 + (K - cnt_gt)*thr) / K.

#define NCLASS 128
#define NREP 8
#define TPB 256
#define REF_GRID 256

typedef float v4f __attribute__((ext_vector_type(4)));

struct Scalars {
  unsigned sel1;
  unsigned cnt_above;   // count strictly above sel1 bin (after pass 1)
  int krem;             // remaining rank within sel1 bin
};

__device__ __forceinline__ unsigned suffix_incl_u(unsigned x, int lane) {
#pragma unroll
  for (int off = 1; off < 64; off <<= 1) {
    unsigned v = __shfl_down(x, off, 64);
    if (lane + off < 64) x += v;
  }
  return x;
}

__device__ __forceinline__ double xor_reduce_d(double x) {
#pragma unroll
  for (int off = 32; off > 0; off >>= 1) x += __shfl_xor(x, off, 64);
  return x;
}

// Descending-rank select on a histogram (nrep replicas summed). Must be called
// by threads 0..63 of one wave. Outputs valid on all 64 lanes.
__device__ __forceinline__ void scan_desc(const unsigned* __restrict__ hist,
                                          int nbins, int nrep, unsigned Ktar,
                                          int* bin_out, unsigned* above_out) {
  const int lane = threadIdx.x;
  const int bpt = nbins >> 6;
  unsigned csum = 0;
  for (int rr = 0; rr < nrep; ++rr) {
    const unsigned* hp = hist + (size_t)rr * nbins + lane * bpt;
    for (int i = 0; i < bpt; ++i) csum += hp[i];
  }
  unsigned suf = suffix_incl_u(csum, lane);
  unsigned long long mask = __ballot(suf >= Ktar);
  int c = 63 - __builtin_clzll(mask);
  unsigned aboveC = __shfl(suf - csum, c, 64);   // strictly above chunk c

  unsigned h = 0;
  if (lane < bpt)
    for (int rr = 0; rr < nrep; ++rr)
      h += hist[(size_t)rr * nbins + c * bpt + lane];
  unsigned suf2 = suffix_incl_u(h, lane);
  unsigned long long mask2 = __ballot((lane < bpt) && (aboveC + suf2 >= Ktar));
  int u = 63 - __builtin_clzll(mask2);
  unsigned above = aboveC + __shfl(suf2 - h, u, 64); // strictly above bin
  *bin_out = c * bpt + u;
  *above_out = above;
}

// ---- node 2: losses + 12-bit histogram. 16 rows/wave, no loop:
//      lane quad (j=lane&3) covers one full 64B line per load instruction;
//      8 loads/lane = 32 elems; 2-level shuffle reductions.
//      Target logit extracted from registers (no scattered gather).
//      Also zeroes hist2/hsum2/sc/fine (aux region) while loads fly. ----
__global__ __launch_bounds__(TPB) void loss_hist_kernel(
    const float* __restrict__ x, const int* __restrict__ tgt,
    float* __restrict__ losses, unsigned* __restrict__ hist1,
    unsigned* __restrict__ zbase, int zwords, int N) {
  __shared__ unsigned lh[4096];
  for (int i = threadIdx.x; i < 4096; i += TPB) lh[i] = 0;

  const int lane = threadIdx.x & 63;
  const int j = lane & 3;        // float4 column group within row
  const int r = lane >> 2;       // row within the wave's 16-row group
  const int wave = blockIdx.x * (TPB / 64) + (threadIdx.x >> 6);
  const int row = wave * 16 + r; // grid exactly covers N

  const v4f* rp = (const v4f*)(x + (size_t)row * NCLASS);
  v4f v0 = __builtin_nontemporal_load(rp + j);
  v4f v1 = __builtin_nontemporal_load(rp + j + 4);
  v4f v2 = __builtin_nontemporal_load(rp + j + 8);
  v4f v3 = __builtin_nontemporal_load(rp + j + 12);
  v4f v4 = __builtin_nontemporal_load(rp + j + 16);
  v4f v5 = __builtin_nontemporal_load(rp + j + 20);
  v4f v6 = __builtin_nontemporal_load(rp + j + 24);
  v4f v7 = __builtin_nontemporal_load(rp + j + 28);
  int t = (j == 0) ? tgt[row] : 0;   // 16 lanes, one coalesced 64B line/wave

  // zero aux buffers (hist2 + hsum2 + sc + fine, ~4.2 MB grid-wide) while
  // the input loads are in flight; refine (next kernel) is the first reader.
  for (int i = blockIdx.x * TPB + threadIdx.x; i < zwords;
       i += gridDim.x * TPB)
    zbase[i] = 0;

  __syncthreads();   // lh zeroed before any atomicAdd below

  // broadcast target index within the 4-lane row quad
  t = __shfl(t, lane & ~3, 64);
  // in-register gather: float index f==t lives in lane with j==(t>>2)&3,
  // register k=t>>4, component t&3.
  float xt = 0.0f;
  if (((t >> 2) & 3) == j) {
    const int k = t >> 4;
    v4f a = (k & 1) ? v1 : v0;
    v4f b = (k & 1) ? v3 : v2;
    v4f c = (k & 1) ? v5 : v4;
    v4f d = (k & 1) ? v7 : v6;
    v4f e = (k & 2) ? b : a;
    v4f f = (k & 2) ? d : c;
    v4f g = (k & 4) ? f : e;
    float lo = (t & 1) ? g.y : g.x;
    float hi = (t & 1) ? g.w : g.z;
    xt = (t & 2) ? hi : lo;
  }
  xt += __shfl_xor(xt, 1, 64);   // quad-sum: non-owners contribute 0
  xt += __shfl_xor(xt, 2, 64);

  float m = fmaxf(fmaxf(fmaxf(v0.x, v0.y), fmaxf(v0.z, v0.w)),
                  fmaxf(fmaxf(v1.x, v1.y), fmaxf(v1.z, v1.w)));
  m = fmaxf(m, fmaxf(fmaxf(fmaxf(v2.x, v2.y), fmaxf(v2.z, v2.w)),
                     fmaxf(fmaxf(v3.x, v3.y), fmaxf(v3.z, v3.w))));
  m = fmaxf(m, fmaxf(fmaxf(fmaxf(v4.x, v4.y), fmaxf(v4.z, v4.w)),
                     fmaxf(fmaxf(v5.x, v5.y), fmaxf(v5.z, v5.w))));
  m = fmaxf(m, fmaxf(fmaxf(fmaxf(v6.x, v6.y), fmaxf(v6.z, v6.w)),
                     fmaxf(fmaxf(v7.x, v7.y), fmaxf(v7.z, v7.w))));
  m = fmaxf(m, __shfl_xor(m, 1, 64));
  m = fmaxf(m, __shfl_xor(m, 2, 64));

  float s = __expf(v0.x - m) + __expf(v0.y - m) + __expf(v0.z - m) + __expf(v0.w - m)
          + __expf(v1.x - m) + __expf(v1.y - m) + __expf(v1.z - m) + __expf(v1.w - m)
          + __expf(v2.x - m) + __expf(v2.y - m) + __expf(v2.z - m) + __expf(v2.w - m)
          + __expf(v3.x - m) + __expf(v3.y - m) + __expf(v3.z - m) + __expf(v3.w - m)
          + __expf(v4.x - m) + __expf(v4.y - m) + __expf(v4.z - m) + __expf(v4.w - m)
          + __expf(v5.x - m) + __expf(v5.y - m) + __expf(v5.z - m) + __expf(v5.w - m)
          + __expf(v6.x - m) + __expf(v6.y - m) + __expf(v6.z - m) + __expf(v6.w - m)
          + __expf(v7.x - m) + __expf(v7.y - m) + __expf(v7.z - m) + __expf(v7.w - m);
  s += __shfl_xor(s, 1, 64);
  s += __shfl_xor(s, 2, 64);

  if (j == 0) {
    float loss = fmaxf(__logf(s) + m - xt, 0.0f);
    losses[row] = loss;
    atomicAdd(&lh[__float_as_uint(loss) >> 20], 1u);
  }
  __syncthreads();
  unsigned* h = hist1 + (size_t)(blockIdx.x & (NREP - 1)) * 4096;
  for (int i = threadIdx.x; i < 4096; i += TPB) {
    unsigned v = lh[i];
    if (v) atomicAdd(&h[i], v);
  }
}

// ---- node 3: self-scan1 + 20-bit refine + hierarchical sums ----
__global__ __launch_bounds__(TPB) void refine_kernel(
    const float* __restrict__ losses, const unsigned* __restrict__ hist1,
    unsigned* __restrict__ hist2, float* __restrict__ hsum2,
    unsigned* __restrict__ fine, Scalars* __restrict__ sc,
    double* __restrict__ partials, int N, int K) {
  __shared__ unsigned lc[1024];
  __shared__ float lsum[1024];
  __shared__ double dsm[TPB / 64];
  __shared__ unsigned sel1_sh;
  for (int i = threadIdx.x; i < 1024; i += TPB) { lc[i] = 0; lsum[i] = 0.0f; }

  // redundant per-block scan1 (reads 128 KiB of L2-hot hist1)
  if (threadIdx.x < 64) {
    int bin; unsigned above;
    scan_desc(hist1, 4096, NREP, (unsigned)K, &bin, &above);
    if (threadIdx.x == 0) {
      sel1_sh = (unsigned)bin;
      if (blockIdx.x == 0) {       // publish for final_kernel
        sc->sel1 = (unsigned)bin;
        sc->cnt_above = above;
        sc->krem = K - (int)above;
      }
    }
  }
  __syncthreads();

  const int lane = threadIdx.x & 63;
  const unsigned sel1 = sel1_sh;
  const float4* L4 = (const float4*)losses;
  const int n4 = N >> 2;
  double accS1 = 0.0;   // sum of elements in coarse bins strictly above sel1
  for (int idx = blockIdx.x * TPB + threadIdx.x; idx < n4;
       idx += REF_GRID * TPB) {
    float4 v = L4[idx];
#pragma unroll
    for (int comp = 0; comp < 4; ++comp) {
      float f = (comp == 0) ? v.x : (comp == 1) ? v.y : (comp == 2) ? v.z : v.w;
      unsigned b = __float_as_uint(f);
      unsigned hi = b >> 20;
      if (hi > sel1) {
        accS1 += (double)f;
      } else if (hi == sel1) {
        atomicAdd(&lc[(b >> 10) & 1023u], 1u);
        atomicAdd(&lsum[(b >> 10) & 1023u], f);
        atomicAdd(&fine[b & 0xFFFFFu], 1u);
      }
    }
  }
  accS1 = xor_reduce_d(accS1);
  if (lane == 0) dsm[threadIdx.x >> 6] = accS1;
  __syncthreads();
  if (threadIdx.x == 0)
    partials[blockIdx.x] = dsm[0] + dsm[1] + dsm[2] + dsm[3];

  unsigned* h = hist2 + (size_t)(blockIdx.x & (NREP - 1)) * 1024;
  for (int i = threadIdx.x; i < 1024; i += TPB) {
    unsigned c = lc[i];
    if (c) { atomicAdd(&h[i], c); atomicAdd(&hsum2[i], lsum[i]); }
  }
}

// ---- node 4: finalize (single block, 256 threads) ----
__global__ __launch_bounds__(TPB) void final_kernel(
    const unsigned* __restrict__ hist2, const float* __restrict__ hsum2,
    const unsigned* __restrict__ fine, const Scalars* __restrict__ sc,
    const double* __restrict__ partials, float* __restrict__ out, int K) {
  __shared__ double dsm[TPB / 64];
  __shared__ double S1sh;
  const int lane = threadIdx.x & 63;

  // S1 total: one partial per thread (REF_GRID == TPB)
  double s1 = partials[threadIdx.x];
  s1 = xor_reduce_d(s1);
  if (lane == 0) dsm[threadIdx.x >> 6] = s1;
  __syncthreads();
  if (threadIdx.x == 0) S1sh = dsm[0] + dsm[1] + dsm[2] + dsm[3];
  __syncthreads();

  if (threadIdx.x < 64) {
    const unsigned sel1 = sc->sel1;
    const unsigned krem = (unsigned)sc->krem;
    int sel2; unsigned above2;
    scan_desc(hist2, 1024, NREP, krem, &sel2, &above2);
    const unsigned krem2 = krem - above2;

    // S2: sums of 10-bit bins strictly above sel2 (within sel1 bin)
    double s2 = 0.0;
    for (int b = sel2 + 1 + lane; b < 1024; b += 64) s2 += (double)hsum2[b];
    s2 = xor_reduce_d(s2);

    // scan level 3 on fine counts within sel2's region
    const unsigned* freg = fine + ((size_t)sel2 << 10);
    int bin3; unsigned above3;
    scan_desc(freg, 1024, 1, krem2, &bin3, &above3);

    // S3: exact — all elements in a fine bin share the same 32-bit value
    const unsigned pfx = (sel1 << 20) | ((unsigned)sel2 << 10);
    double s3 = 0.0;
    for (int t = bin3 + 1 + lane; t < 1024; t += 64) {
      unsigned c = freg[t];
      if (c) s3 += (double)c * (double)__uint_as_float(pfx | (unsigned)t);
    }
    s3 = xor_reduce_d(s3);

    if (lane == 0) {
      unsigned thr_bits = pfx | (unsigned)bin3;
      unsigned cnt_gt = sc->cnt_above + above2 + above3;
      double thrv = (double)__uint_as_float(thr_bits);
      double mean = (S1sh + s2 + s3 +
                     (double)(K - (int)cnt_gt) * thrv) / (double)K;
      *out = (float)mean;
    }
  }
}

extern "C" void kernel_launch(void* const* d_in, const int* in_sizes, int n_in,
                              void* d_out, int out_size, void* d_ws, size_t ws_size,
                              hipStream_t stream) {
  const float* x = (const float*)d_in[0];
  const int* tgt = (const int*)d_in[1];
  float* out = (float*)d_out;
  int N = in_sizes[1];                 // 262144 rows
  int K = (int)(0.7 * (double)N);      // 183500, matches Python int()

  char* ws = (char*)d_ws;
  const size_t OFF_H1 = (size_t)N * 4;                       // losses: 1 MiB
  const size_t OFF_H2 = OFF_H1 + (size_t)NREP * 4096 * 4;    // hist1: 128 KiB
  const size_t OFF_HS = OFF_H2 + (size_t)NREP * 1024 * 4;    // hist2: 32 KiB
  const size_t OFF_SC = OFF_HS + 1024 * 4;                   // hsum2: 4 KiB
  const size_t OFF_FN = OFF_SC + 128;                        // scalars
  const size_t OFF_PT = OFF_FN + (size_t)(1u << 20) * 4;     // fine: 4 MiB
  // partials: REF_GRID doubles after OFF_PT (written before read; no zeroing)

  float* losses = (float*)ws;
  unsigned* hist1 = (unsigned*)(ws + OFF_H1);
  unsigned* hist2 = (unsigned*)(ws + OFF_H2);
  float* hsum2 = (float*)(ws + OFF_HS);
  Scalars* sc = (Scalars*)(ws + OFF_SC);
  unsigned* fine = (unsigned*)(ws + OFF_FN);
  double* partials = (double*)(ws + OFF_PT);

  // pre-zero ONLY hist1 (128 KiB): loss_hist's own atomics race with any
  // in-kernel zeroing of it. hist2/hsum2/sc/fine are zeroed inside
  // loss_hist_kernel (first read by refine, which runs strictly after).
  (void)hipMemsetAsync(ws + OFF_H1, 0, OFF_H2 - OFF_H1, stream);

  const int zwords = (int)((OFF_PT - OFF_H2) / 4);
  loss_hist_kernel<<<N / 64, TPB, 0, stream>>>(x, tgt, losses, hist1,
                                               (unsigned*)(ws + OFF_H2),
                                               zwords, N);
  refine_kernel<<<REF_GRID, TPB, 0, stream>>>(losses, hist1, hist2, hsum2,
                                              fine, sc, partials, N, K);
  final_kernel<<<1, TPB, 0, stream>>>(hist2, hsum2, fine, sc, partials, out, K);
}